// Round 12
// baseline (303.572 us; speedup 1.0000x reference)
//
#include <hip/hip_runtime.h>
#include <hip/hip_bf16.h>
#include <stdint.h>

typedef unsigned short u16;
#define DEVFN static __device__ __forceinline__

typedef __attribute__((ext_vector_type(8))) short bf16x8;
typedef __attribute__((ext_vector_type(4))) float f32x4;

constexpr int   kB   = 64;
constexpr int   kN   = 4096;
constexpr float kEPS = 1e-8f;
constexpr float kLNE = 1e-5f;
constexpr float kKSC = 0.08838834764831845f;  // SLOT^-0.5
constexpr float kISC = 0.125f;                 // I^-0.5

DEVFN u16 f2bf(float f) {
    union { float f; uint32_t u; } x; x.f = f;
    uint32_t r = (x.u + 0x7fffu + ((x.u >> 16) & 1u)) >> 16;
    return (u16)r;
}
DEVFN uint32_t pk2(float lo, float hi) {
    __hip_bfloat162 h = __float22bfloat162_rn(make_float2(lo, hi));
    uint32_t u; __builtin_memcpy(&u, &h, 4); return u;
}
DEVFN u16 bf1(float f) {
    __hip_bfloat16 h = __float2bfloat16(f);
    u16 u; __builtin_memcpy(&u, &h, 2); return u;
}
DEVFN float sigf(float x) { return 1.0f / (1.0f + __expf(-x)); }
DEVFN float read_tau(const void* taup) {
    float inv_tau = 1.0f;
    int iv = *(const int*)taup;
    if (iv > 0 && iv < 1000000) inv_tau = 1.0f / (float)iv;
    else {
        float fv = *(const float*)taup;
        if (fv > 1e-6f && fv < 1e6f) inv_tau = 1.0f / fv;
    }
    return inv_tau;
}

// ---------------- S: fused setup ----------------
__global__ void ksetup(const float* __restrict__ ext_mu, const float* __restrict__ ext_ls,
                       const float* __restrict__ int_mu, const float* __restrict__ int_ls,
                       const float* __restrict__ ext_noise, const float* __restrict__ int_noise,
                       float* __restrict__ sext, float* __restrict__ lpi,
                       const float* __restrict__ Wk, const float* __restrict__ Wv,
                       u16* __restrict__ WT,
                       const float* __restrict__ protos, const float* __restrict__ Wp,
                       const float* __restrict__ lpg, const float* __restrict__ lpb,
                       float* __restrict__ p, float* __restrict__ pT)
{
    __shared__ float pl[64][65];
    __shared__ float mS[64], sS[64];
    const int blk = blockIdx.x;   // 257
    const int t = threadIdx.x;    // 256
    if (blk < 128) {
        int idx = blk * 256 + t;
        int e = idx & 63;
        sext[idx] = ext_mu[e] + __expf(ext_ls[e]) * ext_noise[idx];
        lpi[idx]  = int_mu[e] + __expf(int_ls[e]) * int_noise[idx];
        return;
    }
    if (blk < 256) {
        int idx = (blk - 128) * 256 + t;
        int k = idx >> 8, c = idx & 255;
        float v = (c < 128) ? Wk[k * 128 + c] * kKSC : Wv[k * 128 + (c - 128)];
        WT[(size_t)c * 128 + k] = f2bf(v);
        return;
    }
    for (int idx = t; idx < 64 * 64; idx += 256) pl[idx >> 6][idx & 63] = protos[idx];
    __syncthreads();
    if (t < 64) {
        float sm = 0.f, sq = 0.f;
        for (int k = 0; k < 64; ++k) { float v = pl[t][k]; sm += v; sq += v * v; }
        float m = sm * (1.0f / 64.0f);
        float var = sq * (1.0f / 64.0f) - m * m;
        mS[t] = m; sS[t] = rsqrtf(var + kLNE);
    }
    __syncthreads();
    for (int idx = t; idx < 64 * 64; idx += 256) {
        int r = idx >> 6, c = idx & 63;
        pl[r][c] = (pl[r][c] - mS[r]) * sS[r] * lpg[c] + lpb[c];
    }
    __syncthreads();
    for (int idx = t; idx < 64 * 64; idx += 256) {
        int r = idx >> 6, c = idx & 63;
        float acc = 0.f;
        for (int k = 0; k < 64; ++k) acc += pl[r][k] * Wp[k * 64 + c];
        p[r * 64 + c] = acc;
        pT[c * 64 + r] = acc;
    }
}

// ---------------- K1: pi softmax, slots_int, slots build, q (512 blocks) ----------------
__global__ void kslots(const float* __restrict__ lpi, const float* __restrict__ gum,
                       const void* __restrict__ taup,
                       const float* __restrict__ p,
                       const float* __restrict__ sbck, const float* __restrict__ sext,
                       const float* __restrict__ Wq,
                       float* __restrict__ sint, float* __restrict__ q)
{
    __shared__ float piL[64];
    __shared__ float sv[128];
    const int bs = blockIdx.x;     // 512
    const int t = threadIdx.x;     // 128
    const int b = bs >> 3, s = bs & 7;
    const float inv_tau = read_tau(taup);
    if (t < 64) {
        float l = (lpi[bs * 64 + t] + gum[bs * 64 + t]) * inv_tau;
        float m = l;
        #pragma unroll
        for (int d = 32; d >= 1; d >>= 1) m = fmaxf(m, __shfl_xor(m, d));
        float e = __expf(l - m);
        float smv = e;
        #pragma unroll
        for (int d = 32; d >= 1; d >>= 1) smv += __shfl_xor(smv, d);
        piL[t] = e / smv;
    }
    __syncthreads();
    if (t < 64) {
        float acc = 0.f;
        for (int c = 0; c < 64; ++c) acc += piL[c] * p[c * 64 + t];
        sint[bs * 64 + t] = acc;
        if (s == 0) {
            sv[t]      = sbck[b * 128 + t];
            sv[64 + t] = sbck[b * 128 + 64 + t];
        } else {
            sv[t]      = acc;
            sv[64 + t] = sext[bs * 64 + t];
        }
    }
    __syncthreads();
    {
        float acc = 0.f;
        for (int k = 0; k < 128; ++k) acc += sv[k] * Wq[k * 128 + t];
        q[bs * 128 + t] = acc;
    }
}

// ---------------- A1: LN + kk/vvT GEMM + fused iter-0 attn; 2-tile pipeline ----------------
// 2048 blocks x 256 threads; 2 tiles (same b) per block; both tiles' loads issued up front.
__global__ __launch_bounds__(256) void kmain(const float* __restrict__ inputs,
                                             const u16* __restrict__ WT,
                                             const float* __restrict__ lng, const float* __restrict__ lnb,
                                             const float* __restrict__ q0,
                                             u16* __restrict__ kk, u16* __restrict__ vvT,
                                             float* __restrict__ vpart,
                                             float* __restrict__ pu, float* __restrict__ pcs)
{
    __shared__ u16 At[64 * 128];      // x_hat tile -> kk bounce (16KB)
    __shared__ u16 Bt[128 * 64];      // vvT bounce (16KB)
    __shared__ u16 qbf[16 * 128];     // q0 bf16, rows 8..15 zero (4KB)
    __shared__ u16 aB[2][16][40];
    __shared__ float pwU[2][8][132];
    __shared__ float csL[2][8];
    const int t = threadIdx.x;
    const int g0 = blockIdx.x * 2;        // tiles g0, g0+1 (always same b)
    const int b = g0 >> 6;

    const int w  = t >> 6;
    const int l  = t & 63;
    const int lg = l >> 4;
    const int lr = l & 15;
    const bool iskk = (w < 2);
    const int col4 = t & 31;
    const float4 g4 = ((const float4*)lng)[col4];
    const float4 b4 = ((const float4*)lnb)[col4];

    // stage q0 once (same b for both tiles)
    {
        float4 v = ((const float4*)(q0 + (size_t)b * 1024))[t];
        uint2 pk;
        pk.x = pk2(v.x, v.y);
        pk.y = pk2(v.z, v.w);
        *(uint2*)&qbf[(t >> 5) * 128 + (t & 31) * 4] = pk;
        ((uint32_t*)qbf)[512 + t] = 0u;
        ((uint32_t*)qbf)[768 + t] = 0u;
    }

    // issue BOTH tiles' loads; B's stay outstanding through A's pipeline
    f32x4 xvA[8], xvB[8];
    {
        const float* inpA = inputs + ((size_t)(b * kN) + (size_t)(g0 & 63) * 64) * 128;
        const float* inpB = inpA + 64 * 128;
        #pragma unroll
        for (int j = 0; j < 8; ++j)
            xvA[j] = __builtin_nontemporal_load(((const f32x4*)inpA) + t + j * 256);
        #pragma unroll
        for (int j = 0; j < 8; ++j)
            xvB[j] = __builtin_nontemporal_load(((const f32x4*)inpB) + t + j * 256);
    }

    auto tile = [&](f32x4 (&xv)[8], const int g) {
        const int n0 = (g & 63) * 64;
        // LN + pack
        float s[8], qq[8];
        #pragma unroll
        for (int j = 0; j < 8; ++j) {
            s[j]  = xv[j][0] + xv[j][1] + xv[j][2] + xv[j][3];
            qq[j] = xv[j][0] * xv[j][0] + xv[j][1] * xv[j][1] + xv[j][2] * xv[j][2] + xv[j][3] * xv[j][3];
        }
        #pragma unroll
        for (int d = 16; d >= 1; d >>= 1) {
            #pragma unroll
            for (int j = 0; j < 8; ++j) {
                s[j]  += __shfl_xor(s[j], d);
                qq[j] += __shfl_xor(qq[j], d);
            }
        }
        #pragma unroll
        for (int j = 0; j < 8; ++j) {
            const int row = (t >> 5) + 8 * j;
            const float m   = s[j] * (1.0f / 128.0f);
            const float var = qq[j] * (1.0f / 128.0f) - m * m;
            const float sc  = rsqrtf(var + kLNE);
            uint32_t p0 = pk2((xv[j][0] - m) * sc * g4.x + b4.x, (xv[j][1] - m) * sc * g4.y + b4.y);
            uint32_t p1 = pk2((xv[j][2] - m) * sc * g4.z + b4.z, (xv[j][3] - m) * sc * g4.w + b4.w);
            const int byteoff = row * 256 + (((col4 >> 1) ^ (row & 7)) << 4) + ((col4 & 1) << 3);
            *(uint2*)((char*)At + byteoff) = make_uint2(p0, p1);
        }
        __syncthreads();

        f32x4 acc[4][4];
        #pragma unroll
        for (int i = 0; i < 4; ++i)
            #pragma unroll
            for (int j = 0; j < 4; ++j) acc[i][j] = (f32x4){0.f, 0.f, 0.f, 0.f};
        #pragma unroll
        for (int ks = 0; ks < 4; ++ks) {
            bf16x8 wf[4], xf[4];
            #pragma unroll
            for (int i = 0; i < 4; ++i)
                wf[i] = *(const bf16x8*)(WT + (size_t)(w * 64 + 16 * i + lr) * 128 + ks * 32 + lg * 8);
            #pragma unroll
            for (int i = 0; i < 4; ++i) {
                const int r2 = 16 * i + lr;
                const int chunk = (ks * 4 + lg) ^ (r2 & 7);
                xf[i] = *(const bf16x8*)((const char*)At + r2 * 256 + chunk * 16);
            }
            if (iskk) {
                #pragma unroll
                for (int i = 0; i < 4; ++i)
                    #pragma unroll
                    for (int j = 0; j < 4; ++j)
                        acc[i][j] = __builtin_amdgcn_mfma_f32_16x16x32_bf16(wf[i], xf[j], acc[i][j], 0, 0, 0);
            } else {
                #pragma unroll
                for (int i = 0; i < 4; ++i)
                    #pragma unroll
                    for (int j = 0; j < 4; ++j)
                        acc[i][j] = __builtin_amdgcn_mfma_f32_16x16x32_bf16(xf[i], wf[j], acc[i][j], 0, 0, 0);
            }
        }
        __syncthreads();   // At reads done -> reuse as kk bounce

        if (iskk) {
            #pragma unroll
            for (int cm = 0; cm < 4; ++cm) {
                const int c0 = w * 64 + 16 * cm + lg * 4;
                #pragma unroll
                for (int nn = 0; nn < 4; ++nn) {
                    const int row = 16 * nn + lr;
                    uint2 pk;
                    pk.x = pk2(acc[cm][nn][0], acc[cm][nn][1]);
                    pk.y = pk2(acc[cm][nn][2], acc[cm][nn][3]);
                    const int byteoff = row * 256 + ((((c0 * 2) >> 4) ^ (row & 7)) << 4) + ((c0 * 2) & 15);
                    *(uint2*)((char*)At + byteoff) = pk;
                }
            }
        } else {
            #pragma unroll
            for (int ct = 0; ct < 4; ++ct) {
                const int d = (w - 2) * 64 + 16 * ct + lr;
                #pragma unroll
                for (int m = 0; m < 4; ++m) {
                    const int nn0 = 16 * m + lg * 4;
                    uint2 pk;
                    pk.x = pk2(acc[m][ct][0], acc[m][ct][1]);
                    pk.y = pk2(acc[m][ct][2], acc[m][ct][3]);
                    const int byteoff = d * 128 + ((((nn0 * 2) >> 4) ^ (d & 7)) << 4) + ((nn0 * 2) & 15);
                    *(uint2*)((char*)Bt + byteoff) = pk;
                }
                float sv = 0.f;
                #pragma unroll
                for (int m = 0; m < 4; ++m)
                    #pragma unroll
                    for (int r = 0; r < 4; ++r) sv += acc[m][ct][r];
                sv += __shfl_xor(sv, 16);
                sv += __shfl_xor(sv, 32);
                if (lg == 0) __builtin_nontemporal_store(sv, &vpart[(size_t)g * 128 + d]);
            }
        }
        __syncthreads();

        // copy-out (regular stores -> L2/L3-resident for kattn iters 1,2)
        {
            const size_t kkbase = ((size_t)(b * kN) + n0) * 128;
            #pragma unroll
            for (int j = 0; j < 4; ++j) {
                const int cid = t + j * 256;
                const int row = cid >> 4, ci = cid & 15;
                uint4 v = *(const uint4*)((const char*)At + row * 256 + ((ci ^ (row & 7)) << 4));
                *(uint4*)(kk + kkbase + row * 128 + ci * 8) = v;
            }
            const size_t vvbase = (size_t)b * 128 * (size_t)kN + n0;
            #pragma unroll
            for (int j = 0; j < 4; ++j) {
                const int cid = t + j * 256;
                const int d = cid >> 3, ci = cid & 7;
                uint4 v = *(const uint4*)((const char*)Bt + d * 128 + ((ci ^ (d & 7)) << 4));
                *(uint4*)(vvT + vvbase + (size_t)d * kN + ci * 8) = v;
            }
        }

        // fused iter-0 attention (waves 0,1: 32 rows each)
        if (w < 2) {
            bf16x8 qf[4];
            #pragma unroll
            for (int ks = 0; ks < 4; ++ks)
                qf[ks] = *(const bf16x8*)&qbf[lr * 128 + ks * 32 + lg * 8];
            f32x4 apv[8];
            #pragma unroll
            for (int dt = 0; dt < 8; ++dt) apv[dt] = (f32x4){0.f, 0.f, 0.f, 0.f};
            float cs0 = 0.f, cs1 = 0.f, cs2 = 0.f, cs3 = 0.f;
            #pragma unroll
            for (int c2 = 0; c2 < 2; ++c2) {
                const int rbase = w * 32 + c2 * 16;
                f32x4 plg = (f32x4){0.f, 0.f, 0.f, 0.f};
                #pragma unroll
                for (int ks = 0; ks < 4; ++ks) {
                    const int row = rbase + lr;
                    const int chunk = (ks * 4 + lg) ^ (row & 7);
                    bf16x8 bfr = *(const bf16x8*)((const char*)At + row * 256 + chunk * 16);
                    plg = __builtin_amdgcn_mfma_f32_16x16x32_bf16(qf[ks], bfr, plg, 0, 0, 0);
                }
                float m = fmaxf(fmaxf(plg[0], plg[1]), fmaxf(plg[2], plg[3]));
                m = fmaxf(m, __shfl_xor(m, 16));
                float e0 = __expf(plg[0] - m), e1 = __expf(plg[1] - m);
                float e2 = __expf(plg[2] - m), e3 = __expf(plg[3] - m);
                float smv = e0 + e1 + e2 + e3;
                smv += __shfl_xor(smv, 16);
                const float inv = 1.0f / smv;
                const float a0 = e0 * inv, a1 = e1 * inv, a2 = e2 * inv, a3 = e3 * inv;
                if (lg < 2) {
                    cs0 += a0; cs1 += a1; cs2 += a2; cs3 += a3;
                    const int s0 = lg * 4, nn = c2 * 16 + lr;
                    aB[w][s0 + 0][nn] = bf1(a0);
                    aB[w][s0 + 1][nn] = bf1(a1);
                    aB[w][s0 + 2][nn] = bf1(a2);
                    aB[w][s0 + 3][nn] = bf1(a3);
                }
            }
            bf16x8 af = *(const bf16x8*)&aB[w][lr][lg * 8];
            #pragma unroll
            for (int dt = 0; dt < 8; ++dt) {
                const int d = 16 * dt + lr;
                const int nc = (4 * w + lg) ^ (d & 7);
                bf16x8 vfr = *(const bf16x8*)((const char*)Bt + d * 128 + nc * 16);
                apv[dt] = __builtin_amdgcn_mfma_f32_16x16x32_bf16(vfr, af, apv[dt], 0, 0, 0);
            }
            if (lr < 8) {
                #pragma unroll
                for (int dt = 0; dt < 8; ++dt)
                    *(float4*)&pwU[w][lr][16 * dt + lg * 4] =
                        make_float4(apv[dt][0], apv[dt][1], apv[dt][2], apv[dt][3]);
            }
            #pragma unroll
            for (int d2 = 8; d2 >= 1; d2 >>= 1) {
                cs0 += __shfl_xor(cs0, d2); cs1 += __shfl_xor(cs1, d2);
                cs2 += __shfl_xor(cs2, d2); cs3 += __shfl_xor(cs3, d2);
            }
            if (lr == 0 && lg < 2) {
                csL[w][lg * 4 + 0] = cs0; csL[w][lg * 4 + 1] = cs1;
                csL[w][lg * 4 + 2] = cs2; csL[w][lg * 4 + 3] = cs3;
            }
        }
        __syncthreads();
        {
            const int s2 = t >> 5, dq = t & 31;
            float4 r0 = *(const float4*)&pwU[0][s2][dq * 4];
            float4 r1 = *(const float4*)&pwU[1][s2][dq * 4];
            *(float4*)(pu + (size_t)g * 1024 + s2 * 128 + dq * 4) =
                make_float4(r0.x + r1.x, r0.y + r1.y, r0.z + r1.z, r0.w + r1.w);
        }
        if (t < 8) pcs[g * 8 + t] = csL[0][t] + csL[1][t];
        __syncthreads();   // end-of-tile: safe to overwrite LDS next tile
    };

    tile(xvA, g0);
    tile(xvB, g0 + 1);
}

// ---------------- A3: reduce vvsum partials ----------------
__global__ void kvvsum(const float* __restrict__ part, float* __restrict__ vvsum)
{
    int t = blockIdx.x * 256 + threadIdx.x;  // 8192
    int b = t >> 7, c = t & 127;
    float s = 0.f;
    const float* pp = part + (size_t)b * 64 * 128 + c;
    for (int nb = 0; nb < 64; ++nb) s += pp[nb * 128];
    vvsum[t] = s;
}

// ---------------- K2: attention pass (iters 1,2) ----------------
__global__ __launch_bounds__(256) void kattn(const u16* __restrict__ kk, const u16* __restrict__ vvT,
                                             const float* __restrict__ q,
                                             float* __restrict__ attn_out,
                                             float* __restrict__ pu, float* __restrict__ pcs,
                                             const int wvis)
{
    __shared__ u16 qbf[16][128];
    __shared__ u16 aB[4][16][40];
    __shared__ float pwU[4][8][132];
    __shared__ float csL[4][8];
    const int t = threadIdx.x;
    const int blk = blockIdx.x;        // 1024
    const int b = blk >> 4;
    const int nb = blk & 15;
    const int w = t >> 6, l = t & 63, lg = l >> 4, lr = l & 15;

    {
        float4 v = ((const float4*)(q + (size_t)b * 1024))[t];
        uint2 pk;
        pk.x = pk2(v.x, v.y);
        pk.y = pk2(v.z, v.w);
        *(uint2*)&qbf[t >> 5][(t & 31) * 4] = pk;
        ((uint32_t*)qbf)[512 + t] = 0u;
        ((uint32_t*)qbf)[768 + (t & 255)] = 0u;
    }
    __syncthreads();

    bf16x8 qf[4];
    #pragma unroll
    for (int ks = 0; ks < 4; ++ks) qf[ks] = *(const bf16x8*)&qbf[lr][ks * 32 + lg * 8];

    f32x4 apv[8];
    #pragma unroll
    for (int dt = 0; dt < 8; ++dt) apv[dt] = (f32x4){0.f, 0.f, 0.f, 0.f};
    float cs0 = 0.f, cs1 = 0.f, cs2 = 0.f, cs3 = 0.f;

    const size_t kkb = (size_t)(b * kN) * 128;
    const size_t vvb = (size_t)b * 128 * (size_t)kN;

    #pragma unroll
    for (int ch = 0; ch < 2; ++ch) {
        const int nbase = nb * 256 + w * 64 + ch * 32;
        #pragma unroll
        for (int c2 = 0; c2 < 2; ++c2) {
            const int n16 = nbase + 16 * c2;
            f32x4 pl = (f32x4){0.f, 0.f, 0.f, 0.f};
            #pragma unroll
            for (int ks = 0; ks < 4; ++ks) {
                bf16x8 bfr = *(const bf16x8*)(kk + kkb + (size_t)(n16 + lr) * 128 + ks * 32 + lg * 8);
                pl = __builtin_amdgcn_mfma_f32_16x16x32_bf16(qf[ks], bfr, pl, 0, 0, 0);
            }
            float m = fmaxf(fmaxf(pl[0], pl[1]), fmaxf(pl[2], pl[3]));
            m = fmaxf(m, __shfl_xor(m, 16));
            float e0 = __expf(pl[0] - m), e1 = __expf(pl[1] - m);
            float e2 = __expf(pl[2] - m), e3 = __expf(pl[3] - m);
            float smv = e0 + e1 + e2 + e3;
            smv += __shfl_xor(smv, 16);
            const float inv = 1.0f / smv;
            const float a0 = e0 * inv, a1 = e1 * inv, a2 = e2 * inv, a3 = e3 * inv;
            if (lg < 2) {
                cs0 += a0; cs1 += a1; cs2 += a2; cs3 += a3;
                if (wvis)
                    *(float4*)(attn_out + ((size_t)(b * kN) + n16 + lr) * 8 + lg * 4) =
                        make_float4(a0, a1, a2, a3);
                const int s0 = lg * 4, nn = 16 * c2 + lr;
                aB[w][s0 + 0][nn] = bf1(a0);
                aB[w][s0 + 1][nn] = bf1(a1);
                aB[w][s0 + 2][nn] = bf1(a2);
                aB[w][s0 + 3][nn] = bf1(a3);
            }
        }
        bf16x8 af = *(const bf16x8*)&aB[w][lr][lg * 8];
        #pragma unroll
        for (int dt = 0; dt < 8; ++dt) {
            bf16x8 vfr = *(const bf16x8*)(vvT + vvb + (size_t)(16 * dt + lr) * kN + nbase + lg * 8);
            apv[dt] = __builtin_amdgcn_mfma_f32_16x16x32_bf16(vfr, af, apv[dt], 0, 0, 0);
        }
    }

    if (lr < 8) {
        #pragma unroll
        for (int dt = 0; dt < 8; ++dt)
            *(float4*)&pwU[w][lr][16 * dt + lg * 4] =
                make_float4(apv[dt][0], apv[dt][1], apv[dt][2], apv[dt][3]);
    }
    #pragma unroll
    for (int d = 8; d >= 1; d >>= 1) {
        cs0 += __shfl_xor(cs0, d); cs1 += __shfl_xor(cs1, d);
        cs2 += __shfl_xor(cs2, d); cs3 += __shfl_xor(cs3, d);
    }
    if (lr == 0 && lg < 2) {
        csL[w][lg * 4 + 0] = cs0; csL[w][lg * 4 + 1] = cs1;
        csL[w][lg * 4 + 2] = cs2; csL[w][lg * 4 + 3] = cs3;
    }
    __syncthreads();
    {
        const int s = t >> 5, dq = t & 31;
        float4 r0 = *(const float4*)&pwU[0][s][dq * 4];
        float4 r1 = *(const float4*)&pwU[1][s][dq * 4];
        float4 r2 = *(const float4*)&pwU[2][s][dq * 4];
        float4 r3 = *(const float4*)&pwU[3][s][dq * 4];
        float4 o;
        o.x = r0.x + r1.x + r2.x + r3.x;
        o.y = r0.y + r1.y + r2.y + r3.y;
        o.z = r0.z + r1.z + r2.z + r3.z;
        o.w = r0.w + r1.w + r2.w + r3.w;
        *(float4*)(pu + (size_t)blk * 1024 + s * 128 + dq * 4) = o;
    }
    if (t < 8) pcs[blk * 8 + t] = csL[0][t] + csL[1][t] + csL[2][t] + csL[3][t];
}

// ---------------- K3: updates, GRUs, MLPs, new logits; fused next-iter slots/q ----------------
__global__ __launch_bounds__(256) void kupdate(
    const float* __restrict__ pu, const float* __restrict__ pcs, const int nblk,
    const float* __restrict__ vvsum, float* __restrict__ sint,
    float* __restrict__ sext, float* __restrict__ lpi,
    const float* __restrict__ giWih, const float* __restrict__ giWhh,
    const float* __restrict__ gibih, const float* __restrict__ gibhh,
    const float* __restrict__ geWih, const float* __restrict__ geWhh,
    const float* __restrict__ gebih, const float* __restrict__ gebhh,
    const float* __restrict__ miW1, const float* __restrict__ mib1,
    const float* __restrict__ miW2, const float* __restrict__ mib2,
    const float* __restrict__ meW1, const float* __restrict__ meb1,
    const float* __restrict__ meW2, const float* __restrict__ meb2,
    const float* __restrict__ lmig, const float* __restrict__ lmib,
    const float* __restrict__ lmeg, const float* __restrict__ lmeb,
    const float* __restrict__ pT, float* __restrict__ out, const int last,
    const float* __restrict__ gumN, const void* __restrict__ taup,
    const float* __restrict__ p, const float* __restrict__ sbck,
    const float* __restrict__ Wq, float* __restrict__ q)
{
    __shared__ float uL[128], hA[64], hB[64];
    __shared__ float g1[192], g2[192];
    __shared__ float tmp[256];
    __shared__ float red[256];
    __shared__ float outE[64], outI[64];
    __shared__ float lgL[64];
    __shared__ float sv[128];
    const int bs = blockIdx.x;   // 512
    const int b = bs >> 3, s = bs & 7;
    const int t = threadIdx.x;   // 256

    if (t < 128) {
        float num = 0.f;
        for (int nb = 0; nb < nblk; ++nb) num += pu[((size_t)(b * nblk + nb)) * 1024 + s * 128 + t];
        float den = 4096.0f * kEPS;
        for (int nb = 0; nb < nblk; ++nb) den += pcs[(b * nblk + nb) * 8 + s];
        uL[t] = (num + kEPS * vvsum[b * 128 + t]) / den;
    } else if (t < 192) {
        hA[t - 128] = sext[bs * 64 + (t - 128)];
    } else {
        hB[t - 192] = sint[bs * 64 + (t - 192)];
    }
    __syncthreads();
    if (t < 192) {
        float a = gebih[t], bb = gebhh[t];
        for (int k = 0; k < 64; ++k) {
            a  = fmaf(uL[64 + k], geWih[k * 192 + t], a);
            bb = fmaf(hA[k],      geWhh[k * 192 + t], bb);
        }
        g1[t] = a; g2[t] = bb;
    }
    __syncthreads();
    if (t < 64) {
        float r = sigf(g1[t] + g2[t]);
        float z = sigf(g1[64 + t] + g2[64 + t]);
        float nn = tanhf(g1[128 + t] + r * g2[128 + t]);
        outE[t] = (1.0f - z) * nn + z * hA[t];
    }
    __syncthreads();
    if (t < 192) {
        float a = gibih[t], bb = gibhh[t];
        for (int k = 0; k < 64; ++k) {
            a  = fmaf(uL[k], giWih[k * 192 + t], a);
            bb = fmaf(hB[k], giWhh[k * 192 + t], bb);
        }
        g1[t] = a; g2[t] = bb;
    }
    __syncthreads();
    if (t < 64) {
        float r = sigf(g1[t] + g2[t]);
        float z = sigf(g1[64 + t] + g2[64 + t]);
        float nn = tanhf(g1[128 + t] + r * g2[128 + t]);
        outI[t] = (1.0f - z) * nn + z * hB[t];
    }
    __syncthreads();
    if (!last) {
        // MLP ext
        if (t < 64) {
            float v = outE[t];
            float sm = v, sq = v * v;
            #pragma unroll
            for (int d = 32; d >= 1; d >>= 1) { sm += __shfl_xor(sm, d); sq += __shfl_xor(sq, d); }
            float m = sm * (1.0f / 64.0f), var = sq * (1.0f / 64.0f) - m * m;
            g1[t] = (v - m) * rsqrtf(var + kLNE) * lmeg[t] + lmeb[t];
        }
        __syncthreads();
        {
            float a = meb1[t];
            for (int k = 0; k < 64; ++k) a = fmaf(g1[k], meW1[k * 256 + t], a);
            tmp[t] = fmaxf(a, 0.0f);
        }
        __syncthreads();
        {
            const int c = t & 63, qq = t >> 6;
            float o = 0.f;
            for (int jj = 0; jj < 64; ++jj) {
                const int j = qq * 64 + jj;
                o = fmaf(tmp[j], meW2[j * 64 + c], o);
            }
            red[t] = o;
        }
        __syncthreads();
        if (t < 64) outE[t] += meb2[t] + red[t] + red[64 + t] + red[128 + t] + red[192 + t];
        __syncthreads();
        // MLP int
        if (t < 64) {
            float v = outI[t];
            float sm = v, sq = v * v;
            #pragma unroll
            for (int d = 32; d >= 1; d >>= 1) { sm += __shfl_xor(sm, d); sq += __shfl_xor(sq, d); }
            float m = sm * (1.0f / 64.0f), var = sq * (1.0f / 64.0f) - m * m;
            g1[t] = (v - m) * rsqrtf(var + kLNE) * lmig[t] + lmib[t];
        }
        __syncthreads();
        {
            float a = mib1[t];
            for (int k = 0; k < 64; ++k) a = fmaf(g1[k], miW1[k * 256 + t], a);
            tmp[t] = fmaxf(a, 0.0f);
        }
        __syncthreads();
        {
            const int c = t & 63, qq = t >> 6;
            float o = 0.f;
            for (int jj = 0; jj < 64; ++jj) {
                const int j = qq * 64 + jj;
                o = fmaf(tmp[j], miW2[j * 64 + c], o);
            }
            red[t] = o;
        }
        __syncthreads();
        if (t < 64) outI[t] += mib2[t] + red[t] + red[64 + t] + red[128 + t] + red[192 + t];
        __syncthreads();
    }
    if (t < 64) {
        float lg = 0.f;
        for (int k = 0; k < 64; ++k) lg = fmaf(outI[k], pT[k * 64 + t], lg);
        lg *= kISC;
        lgL[t] = lg;
        if (last) { if (s > 0) out[28672 + (b * 7 + (s - 1)) * 64 + t] = lg; }
    } else if (t < 128) {
        int c = t - 64;
        float v = outE[c];
        sext[bs * 64 + c] = v;
        if (last && s > 0) out[(b * 7 + (s - 1)) * 64 + c] = v;
    }
    if (last) return;

    __syncthreads();
    const float inv_tau = read_tau(taup);
    if (t < 64) {
        float l = (lgL[t] + gumN[bs * 64 + t]) * inv_tau;
        float m = l;
        #pragma unroll
        for (int d = 32; d >= 1; d >>= 1) m = fmaxf(m, __shfl_xor(m, d));
        float e = __expf(l - m);
        float smv = e;
        #pragma unroll
        for (int d = 32; d >= 1; d >>= 1) smv += __shfl_xor(smv, d);
        tmp[t] = e / smv;   // pi
    }
    __syncthreads();
    if (t < 64) {
        float acc = 0.f;
        for (int c = 0; c < 64; ++c) acc += tmp[c] * p[c * 64 + t];
        sint[bs * 64 + t] = acc;
        if (s == 0) {
            sv[t]      = sbck[b * 128 + t];
            sv[64 + t] = sbck[b * 128 + 64 + t];
        } else {
            sv[t]      = acc;
            sv[64 + t] = outE[t];
        }
    }
    __syncthreads();
    if (t < 128) {
        float acc = 0.f;
        for (int k = 0; k < 128; ++k) acc += sv[k] * Wq[k * 128 + t];
        q[bs * 128 + t] = acc;
    }
}

extern "C" void kernel_launch(void* const* d_in, const int* in_sizes, int n_in,
                              void* d_out, int out_size, void* d_ws, size_t ws_size,
                              hipStream_t stream)
{
    (void)in_sizes; (void)n_in; (void)out_size; (void)ws_size;
    const float* slots_bck = (const float*)d_in[0];
    const float* inputs    = (const float*)d_in[1];
    const float* protos    = (const float*)d_in[2];
    const float* ext_noise = (const float*)d_in[3];
    const float* int_noise = (const float*)d_in[4];
    const float* gumbel    = (const float*)d_in[5];
    const void*  taup      = d_in[6];
    const float* ext_mu    = (const float*)d_in[7];
    const float* ext_ls    = (const float*)d_in[8];
    const float* int_mu    = (const float*)d_in[9];
    const float* int_ls    = (const float*)d_in[10];
    const float* ln_in_g   = (const float*)d_in[11];
    const float* ln_in_b   = (const float*)d_in[12];
    const float* ln_p_g    = (const float*)d_in[13];
    const float* ln_p_b    = (const float*)d_in[14];
    const float* ln_mi_g   = (const float*)d_in[15];
    const float* ln_mi_b   = (const float*)d_in[16];
    const float* ln_me_g   = (const float*)d_in[17];
    const float* ln_me_b   = (const float*)d_in[18];
    const float* Wq        = (const float*)d_in[19];
    const float* Wk        = (const float*)d_in[20];
    const float* Wv        = (const float*)d_in[21];
    const float* Wp        = (const float*)d_in[22];
    const float* giWih     = (const float*)d_in[23];
    const float* giWhh     = (const float*)d_in[24];
    const float* gibih     = (const float*)d_in[25];
    const float* gibhh     = (const float*)d_in[26];
    const float* geWih     = (const float*)d_in[27];
    const float* geWhh     = (const float*)d_in[28];
    const float* gebih     = (const float*)d_in[29];
    const float* gebhh     = (const float*)d_in[30];
    const float* miW1      = (const float*)d_in[31];
    const float* mib1      = (const float*)d_in[32];
    const float* miW2      = (const float*)d_in[33];
    const float* mib2      = (const float*)d_in[34];
    const float* meW1      = (const float*)d_in[35];
    const float* meb1      = (const float*)d_in[36];
    const float* meW2      = (const float*)d_in[37];
    const float* meb2      = (const float*)d_in[38];
    float* out = (float*)d_out;

    char* ws = (char*)d_ws;
    size_t o = 0;
    auto alloc = [&](size_t bytes) { size_t r = o; o += (bytes + 255) & ~(size_t)255; return r; };
    u16*   kkp   = (u16*)  (ws + alloc((size_t)kB * kN * 128 * 2));
    u16*   vvTp  = (u16*)  (ws + alloc((size_t)kB * kN * 128 * 2));
    u16*   WT    = (u16*)  (ws + alloc(256 * 128 * 2));
    float* vpart = (float*)(ws + alloc((size_t)4096 * 128 * 4));
    float* vvsum = (float*)(ws + alloc(8192 * 4));
    float* pbuf  = (float*)(ws + alloc(4096 * 4));
    float* pT    = (float*)(ws + alloc(4096 * 4));
    float* sext  = (float*)(ws + alloc(32768 * 4));
    float* lpi   = (float*)(ws + alloc(32768 * 4));
    float* sint  = (float*)(ws + alloc(32768 * 4));
    float* q     = (float*)(ws + alloc(65536 * 4));
    float* pu    = (float*)(ws + alloc((size_t)4096 * 1024 * 4));
    float* pcs   = (float*)(ws + alloc(4096 * 8 * 4));

    ksetup<<<257, 256, 0, stream>>>(ext_mu, ext_ls, int_mu, int_ls, ext_noise, int_noise,
                                    sext, lpi, Wk, Wv, WT, protos, Wp, ln_p_g, ln_p_b, pbuf, pT);
    kslots<<<512, 128, 0, stream>>>(lpi, gumbel, taup, pbuf, slots_bck, sext, Wq, sint, q);
    kmain<<<2048, 256, 0, stream>>>(inputs, WT, ln_in_g, ln_in_b, q, kkp, vvTp, vpart, pu, pcs);
    kvvsum<<<32, 256, 0, stream>>>(vpart, vvsum);

    for (int i = 0; i < 3; ++i) {
        const int last = (i == 2);
        if (i > 0)
            kattn<<<1024, 256, 0, stream>>>(kkp, vvTp, q, out + 57344, pu, pcs, last ? 1 : 0);
        kupdate<<<512, 256, 0, stream>>>(pu, pcs, (i == 0) ? 64 : 16, vvsum, sint, sext, lpi,
                                         giWih, giWhh, gibih, gibhh,
                                         geWih, geWhh, gebih, gebhh,
                                         miW1, mib1, miW2, mib2,
                                         meW1, meb1, meW2, meb2,
                                         ln_mi_g, ln_mi_b, ln_me_g, ln_me_b,
                                         pT, out, last,
                                         gumbel + (size_t)(i + 1 < 3 ? i + 1 : 0) * 32768,
                                         taup, pbuf, slots_bck, Wq, q);
    }
}

// Round 13
// 268.703 us; speedup vs baseline: 1.1298x; 1.1298x over previous
//
#include <hip/hip_runtime.h>
#include <hip/hip_bf16.h>
#include <stdint.h>

typedef unsigned short u16;
#define DEVFN static __device__ __forceinline__

typedef __attribute__((ext_vector_type(8))) short bf16x8;
typedef __attribute__((ext_vector_type(4))) float f32x4;

constexpr int   kB   = 64;
constexpr int   kN   = 4096;
constexpr float kEPS = 1e-8f;
constexpr float kLNE = 1e-5f;
constexpr float kKSC = 0.08838834764831845f;  // SLOT^-0.5
constexpr float kISC = 0.125f;                 // I^-0.5

DEVFN u16 f2bf(float f) {
    union { float f; uint32_t u; } x; x.f = f;
    uint32_t r = (x.u + 0x7fffu + ((x.u >> 16) & 1u)) >> 16;
    return (u16)r;
}
DEVFN uint32_t pk2(float lo, float hi) {
    __hip_bfloat162 h = __float22bfloat162_rn(make_float2(lo, hi));
    uint32_t u; __builtin_memcpy(&u, &h, 4); return u;
}
DEVFN u16 bf1(float f) {
    __hip_bfloat16 h = __float2bfloat16(f);
    u16 u; __builtin_memcpy(&u, &h, 2); return u;
}
DEVFN float sigf(float x) { return 1.0f / (1.0f + __expf(-x)); }
DEVFN float read_tau(const void* taup) {
    float inv_tau = 1.0f;
    int iv = *(const int*)taup;
    if (iv > 0 && iv < 1000000) inv_tau = 1.0f / (float)iv;
    else {
        float fv = *(const float*)taup;
        if (fv > 1e-6f && fv < 1e6f) inv_tau = 1.0f / fv;
    }
    return inv_tau;
}

// ---------------- S: fused setup ----------------
__global__ void ksetup(const float* __restrict__ ext_mu, const float* __restrict__ ext_ls,
                       const float* __restrict__ int_mu, const float* __restrict__ int_ls,
                       const float* __restrict__ ext_noise, const float* __restrict__ int_noise,
                       float* __restrict__ sext, float* __restrict__ lpi,
                       const float* __restrict__ Wk, const float* __restrict__ Wv,
                       u16* __restrict__ WT,
                       const float* __restrict__ protos, const float* __restrict__ Wp,
                       const float* __restrict__ lpg, const float* __restrict__ lpb,
                       float* __restrict__ p, float* __restrict__ pT)
{
    __shared__ float pl[64][65];
    __shared__ float mS[64], sS[64];
    const int blk = blockIdx.x;   // 257
    const int t = threadIdx.x;    // 256
    if (blk < 128) {
        int idx = blk * 256 + t;
        int e = idx & 63;
        sext[idx] = ext_mu[e] + __expf(ext_ls[e]) * ext_noise[idx];
        lpi[idx]  = int_mu[e] + __expf(int_ls[e]) * int_noise[idx];
        return;
    }
    if (blk < 256) {
        int idx = (blk - 128) * 256 + t;
        int k = idx >> 8, c = idx & 255;
        float v = (c < 128) ? Wk[k * 128 + c] * kKSC : Wv[k * 128 + (c - 128)];
        WT[(size_t)c * 128 + k] = f2bf(v);
        return;
    }
    for (int idx = t; idx < 64 * 64; idx += 256) pl[idx >> 6][idx & 63] = protos[idx];
    __syncthreads();
    if (t < 64) {
        float sm = 0.f, sq = 0.f;
        for (int k = 0; k < 64; ++k) { float v = pl[t][k]; sm += v; sq += v * v; }
        float m = sm * (1.0f / 64.0f);
        float var = sq * (1.0f / 64.0f) - m * m;
        mS[t] = m; sS[t] = rsqrtf(var + kLNE);
    }
    __syncthreads();
    for (int idx = t; idx < 64 * 64; idx += 256) {
        int r = idx >> 6, c = idx & 63;
        pl[r][c] = (pl[r][c] - mS[r]) * sS[r] * lpg[c] + lpb[c];
    }
    __syncthreads();
    for (int idx = t; idx < 64 * 64; idx += 256) {
        int r = idx >> 6, c = idx & 63;
        float acc = 0.f;
        for (int k = 0; k < 64; ++k) acc += pl[r][k] * Wp[k * 64 + c];
        p[r * 64 + c] = acc;
        pT[c * 64 + r] = acc;
    }
}

// ---------------- K1: pi softmax, slots_int, slots build, q (512 blocks) ----------------
__global__ void kslots(const float* __restrict__ lpi, const float* __restrict__ gum,
                       const void* __restrict__ taup,
                       const float* __restrict__ p,
                       const float* __restrict__ sbck, const float* __restrict__ sext,
                       const float* __restrict__ Wq,
                       float* __restrict__ sint, float* __restrict__ q)
{
    __shared__ float piL[64];
    __shared__ float sv[128];
    const int bs = blockIdx.x;     // 512
    const int t = threadIdx.x;     // 128
    const int b = bs >> 3, s = bs & 7;
    const float inv_tau = read_tau(taup);
    if (t < 64) {
        float l = (lpi[bs * 64 + t] + gum[bs * 64 + t]) * inv_tau;
        float m = l;
        #pragma unroll
        for (int d = 32; d >= 1; d >>= 1) m = fmaxf(m, __shfl_xor(m, d));
        float e = __expf(l - m);
        float smv = e;
        #pragma unroll
        for (int d = 32; d >= 1; d >>= 1) smv += __shfl_xor(smv, d);
        piL[t] = e / smv;
    }
    __syncthreads();
    if (t < 64) {
        float acc = 0.f;
        for (int c = 0; c < 64; ++c) acc += piL[c] * p[c * 64 + t];
        sint[bs * 64 + t] = acc;
        if (s == 0) {
            sv[t]      = sbck[b * 128 + t];
            sv[64 + t] = sbck[b * 128 + 64 + t];
        } else {
            sv[t]      = acc;
            sv[64 + t] = sext[bs * 64 + t];
        }
    }
    __syncthreads();
    {
        float acc = 0.f;
        for (int k = 0; k < 128; ++k) acc += sv[k] * Wq[k * 128 + t];
        q[bs * 128 + t] = acc;
    }
}

// ---------------- A1: LN + kk/vvT GEMM + FUSED iteration-0 attention (R11-exact) ----------------
// 4096 blocks x 256 threads; 64 rows/block. nt input loads; LDS bounce; regular stores.
__global__ __launch_bounds__(256) void kmain(const float* __restrict__ inputs,
                                             const u16* __restrict__ WT,
                                             const float* __restrict__ lng, const float* __restrict__ lnb,
                                             const float* __restrict__ q0,
                                             u16* __restrict__ kk, u16* __restrict__ vvT,
                                             float* __restrict__ vpart,
                                             float* __restrict__ pu, float* __restrict__ pcs)
{
    __shared__ u16 At[64 * 128];      // x_hat tile -> kk bounce [row][c] (16KB)
    __shared__ u16 Bt[128 * 64];      // vvT bounce [d][ni] (16KB)
    __shared__ u16 qbf[16 * 128];     // q0 bf16, rows 8..15 zero (4KB)
    __shared__ u16 aB[2][16][40];     // attn bounce per attn-wave
    __shared__ float pwU[2][8][132];  // PV partials per attn-wave
    __shared__ float csL[2][8];
    const int t = threadIdx.x;
    const int blk = blockIdx.x;           // 4096
    const int b = blk >> 6;
    const int n0 = (blk & 63) * 64;
    const float* inp = inputs + ((size_t)(b * kN + n0)) * 128;

    // stage q0 (iteration-0 q) as bf16
    {
        float4 v = ((const float4*)(q0 + (size_t)b * 1024))[t];
        uint2 pk;
        pk.x = pk2(v.x, v.y);
        pk.y = pk2(v.z, v.w);
        *(uint2*)&qbf[(t >> 5) * 128 + (t & 31) * 4] = pk;
        ((uint32_t*)qbf)[512 + t] = 0u;
        ((uint32_t*)qbf)[768 + t] = 0u;
    }

    f32x4 xv[8];
    #pragma unroll
    for (int j = 0; j < 8; ++j)
        xv[j] = __builtin_nontemporal_load(((const f32x4*)inp) + t + j * 256);

    float s[8], qq[8];
    #pragma unroll
    for (int j = 0; j < 8; ++j) {
        s[j]  = xv[j][0] + xv[j][1] + xv[j][2] + xv[j][3];
        qq[j] = xv[j][0] * xv[j][0] + xv[j][1] * xv[j][1] + xv[j][2] * xv[j][2] + xv[j][3] * xv[j][3];
    }
    #pragma unroll
    for (int d = 16; d >= 1; d >>= 1) {
        #pragma unroll
        for (int j = 0; j < 8; ++j) {
            s[j]  += __shfl_xor(s[j], d);
            qq[j] += __shfl_xor(qq[j], d);
        }
    }
    const int col4 = t & 31;
    const float4 g4 = ((const float4*)lng)[col4];
    const float4 b4 = ((const float4*)lnb)[col4];
    #pragma unroll
    for (int j = 0; j < 8; ++j) {
        const int row = (t >> 5) + 8 * j;
        const float m   = s[j] * (1.0f / 128.0f);
        const float var = qq[j] * (1.0f / 128.0f) - m * m;
        const float sc  = rsqrtf(var + kLNE);
        uint32_t p0 = pk2((xv[j][0] - m) * sc * g4.x + b4.x, (xv[j][1] - m) * sc * g4.y + b4.y);
        uint32_t p1 = pk2((xv[j][2] - m) * sc * g4.z + b4.z, (xv[j][3] - m) * sc * g4.w + b4.w);
        const int byteoff = row * 256 + (((col4 >> 1) ^ (row & 7)) << 4) + ((col4 & 1) << 3);
        *(uint2*)((char*)At + byteoff) = make_uint2(p0, p1);
    }
    __syncthreads();

    const int w  = t >> 6;       // wave 0..3 -> output cols [64w, 64w+64)
    const int l  = t & 63;
    const int lg = l >> 4;
    const int lr = l & 15;
    const bool iskk = (w < 2);

    f32x4 acc[4][4];
    #pragma unroll
    for (int i = 0; i < 4; ++i)
        #pragma unroll
        for (int j = 0; j < 4; ++j) acc[i][j] = (f32x4){0.f, 0.f, 0.f, 0.f};

    #pragma unroll
    for (int ks = 0; ks < 4; ++ks) {
        bf16x8 wf[4], xf[4];
        #pragma unroll
        for (int i = 0; i < 4; ++i)
            wf[i] = *(const bf16x8*)(WT + (size_t)(w * 64 + 16 * i + lr) * 128 + ks * 32 + lg * 8);
        #pragma unroll
        for (int i = 0; i < 4; ++i) {
            const int r2 = 16 * i + lr;
            const int chunk = (ks * 4 + lg) ^ (r2 & 7);
            xf[i] = *(const bf16x8*)((const char*)At + r2 * 256 + chunk * 16);
        }
        if (iskk) {
            #pragma unroll
            for (int i = 0; i < 4; ++i)
                #pragma unroll
                for (int j = 0; j < 4; ++j)
                    acc[i][j] = __builtin_amdgcn_mfma_f32_16x16x32_bf16(wf[i], xf[j], acc[i][j], 0, 0, 0);
        } else {
            #pragma unroll
            for (int i = 0; i < 4; ++i)
                #pragma unroll
                for (int j = 0; j < 4; ++j)
                    acc[i][j] = __builtin_amdgcn_mfma_f32_16x16x32_bf16(xf[i], wf[j], acc[i][j], 0, 0, 0);
        }
    }

    __syncthreads();   // all At reads done; reuse as kk bounce

    if (iskk) {
        #pragma unroll
        for (int cm = 0; cm < 4; ++cm) {
            const int c0 = w * 64 + 16 * cm + lg * 4;
            #pragma unroll
            for (int nn = 0; nn < 4; ++nn) {
                const int row = 16 * nn + lr;
                uint2 pk;
                pk.x = pk2(acc[cm][nn][0], acc[cm][nn][1]);
                pk.y = pk2(acc[cm][nn][2], acc[cm][nn][3]);
                const int byteoff = row * 256 + ((((c0 * 2) >> 4) ^ (row & 7)) << 4) + ((c0 * 2) & 15);
                *(uint2*)((char*)At + byteoff) = pk;
            }
        }
    } else {
        #pragma unroll
        for (int ct = 0; ct < 4; ++ct) {
            const int d = (w - 2) * 64 + 16 * ct + lr;
            #pragma unroll
            for (int m = 0; m < 4; ++m) {
                const int nn0 = 16 * m + lg * 4;
                uint2 pk;
                pk.x = pk2(acc[m][ct][0], acc[m][ct][1]);
                pk.y = pk2(acc[m][ct][2], acc[m][ct][3]);
                const int byteoff = d * 128 + ((((nn0 * 2) >> 4) ^ (d & 7)) << 4) + ((nn0 * 2) & 15);
                *(uint2*)((char*)Bt + byteoff) = pk;
            }
            float sv = 0.f;
            #pragma unroll
            for (int m = 0; m < 4; ++m)
                #pragma unroll
                for (int r = 0; r < 4; ++r) sv += acc[m][ct][r];
            sv += __shfl_xor(sv, 16);
            sv += __shfl_xor(sv, 32);
            if (lg == 0) __builtin_nontemporal_store(sv, &vpart[(size_t)blk * 128 + d]);
        }
    }
    __syncthreads();

    // coalesced copy-out (regular stores -> L2/L3-resident for kattn iters 1,2)
    {
        const size_t kkbase = ((size_t)(b * kN) + n0) * 128;
        #pragma unroll
        for (int j = 0; j < 4; ++j) {
            const int cid = t + j * 256;
            const int row = cid >> 4, ci = cid & 15;
            uint4 v = *(const uint4*)((const char*)At + row * 256 + ((ci ^ (row & 7)) << 4));
            *(uint4*)(kk + kkbase + row * 128 + ci * 8) = v;
        }
        const size_t vvbase = (size_t)b * 128 * (size_t)kN + n0;
        #pragma unroll
        for (int j = 0; j < 4; ++j) {
            const int cid = t + j * 256;
            const int d = cid >> 3, ci = cid & 7;
            uint4 v = *(const uint4*)((const char*)Bt + d * 128 + ((ci ^ (d & 7)) << 4));
            *(uint4*)(vvT + vvbase + (size_t)d * kN + ci * 8) = v;
        }
    }

    // ---- FUSED iteration-0 attention on LDS-resident tiles (waves 0,1: 32 rows each) ----
    if (w < 2) {
        bf16x8 qf[4];
        #pragma unroll
        for (int ks = 0; ks < 4; ++ks)
            qf[ks] = *(const bf16x8*)&qbf[lr * 128 + ks * 32 + lg * 8];
        f32x4 apv[8];
        #pragma unroll
        for (int dt = 0; dt < 8; ++dt) apv[dt] = (f32x4){0.f, 0.f, 0.f, 0.f};
        float cs0 = 0.f, cs1 = 0.f, cs2 = 0.f, cs3 = 0.f;
        #pragma unroll
        for (int c2 = 0; c2 < 2; ++c2) {
            const int rbase = w * 32 + c2 * 16;   // local row base
            f32x4 plg = (f32x4){0.f, 0.f, 0.f, 0.f};
            #pragma unroll
            for (int ks = 0; ks < 4; ++ks) {
                const int row = rbase + lr;
                const int chunk = (ks * 4 + lg) ^ (row & 7);
                bf16x8 bfr = *(const bf16x8*)((const char*)At + row * 256 + chunk * 16);
                plg = __builtin_amdgcn_mfma_f32_16x16x32_bf16(qf[ks], bfr, plg, 0, 0, 0);
            }
            float m = fmaxf(fmaxf(plg[0], plg[1]), fmaxf(plg[2], plg[3]));
            m = fmaxf(m, __shfl_xor(m, 16));
            float e0 = __expf(plg[0] - m), e1 = __expf(plg[1] - m);
            float e2 = __expf(plg[2] - m), e3 = __expf(plg[3] - m);
            float smv = e0 + e1 + e2 + e3;
            smv += __shfl_xor(smv, 16);
            const float inv = 1.0f / smv;
            const float a0 = e0 * inv, a1 = e1 * inv, a2 = e2 * inv, a3 = e3 * inv;
            if (lg < 2) {
                cs0 += a0; cs1 += a1; cs2 += a2; cs3 += a3;
                const int s0 = lg * 4, nn = c2 * 16 + lr;
                aB[w][s0 + 0][nn] = bf1(a0);
                aB[w][s0 + 1][nn] = bf1(a1);
                aB[w][s0 + 2][nn] = bf1(a2);
                aB[w][s0 + 3][nn] = bf1(a3);
            }
        }
        bf16x8 af = *(const bf16x8*)&aB[w][lr][lg * 8];
        #pragma unroll
        for (int dt = 0; dt < 8; ++dt) {
            const int d = 16 * dt + lr;
            const int nc = (4 * w + lg) ^ (d & 7);
            bf16x8 vfr = *(const bf16x8*)((const char*)Bt + d * 128 + nc * 16);
            apv[dt] = __builtin_amdgcn_mfma_f32_16x16x32_bf16(vfr, af, apv[dt], 0, 0, 0);
        }
        if (lr < 8) {
            #pragma unroll
            for (int dt = 0; dt < 8; ++dt)
                *(float4*)&pwU[w][lr][16 * dt + lg * 4] =
                    make_float4(apv[dt][0], apv[dt][1], apv[dt][2], apv[dt][3]);
        }
        #pragma unroll
        for (int d2 = 8; d2 >= 1; d2 >>= 1) {
            cs0 += __shfl_xor(cs0, d2); cs1 += __shfl_xor(cs1, d2);
            cs2 += __shfl_xor(cs2, d2); cs3 += __shfl_xor(cs3, d2);
        }
        if (lr == 0 && lg < 2) {
            csL[w][lg * 4 + 0] = cs0; csL[w][lg * 4 + 1] = cs1;
            csL[w][lg * 4 + 2] = cs2; csL[w][lg * 4 + 3] = cs3;
        }
    }
    __syncthreads();
    {
        const int s2 = t >> 5, dq = t & 31;
        float4 r0 = *(const float4*)&pwU[0][s2][dq * 4];
        float4 r1 = *(const float4*)&pwU[1][s2][dq * 4];
        *(float4*)(pu + (size_t)blk * 1024 + s2 * 128 + dq * 4) =
            make_float4(r0.x + r1.x, r0.y + r1.y, r0.z + r1.z, r0.w + r1.w);
    }
    if (t < 8) pcs[blk * 8 + t] = csL[0][t] + csL[1][t];
}

// ---------------- A3: reduce vvsum partials ----------------
__global__ void kvvsum(const float* __restrict__ part, float* __restrict__ vvsum)
{
    int t = blockIdx.x * 256 + threadIdx.x;  // 8192
    int b = t >> 7, c = t & 127;
    float s = 0.f;
    const float* pp = part + (size_t)b * 64 * 128 + c;
    for (int nb = 0; nb < 64; ++nb) s += pp[nb * 128];
    vvsum[t] = s;
}

// ---------------- K2: attention pass (iters 1,2) ----------------
__global__ __launch_bounds__(256) void kattn(const u16* __restrict__ kk, const u16* __restrict__ vvT,
                                             const float* __restrict__ q,
                                             float* __restrict__ attn_out,
                                             float* __restrict__ pu, float* __restrict__ pcs,
                                             const int wvis)
{
    __shared__ u16 qbf[16][128];
    __shared__ u16 aB[4][16][40];
    __shared__ float pwU[4][8][132];
    __shared__ float csL[4][8];
    const int t = threadIdx.x;
    const int blk = blockIdx.x;        // 1024
    const int b = blk >> 4;
    const int nb = blk & 15;
    const int w = t >> 6, l = t & 63, lg = l >> 4, lr = l & 15;

    {
        float4 v = ((const float4*)(q + (size_t)b * 1024))[t];
        uint2 pk;
        pk.x = pk2(v.x, v.y);
        pk.y = pk2(v.z, v.w);
        *(uint2*)&qbf[t >> 5][(t & 31) * 4] = pk;
        ((uint32_t*)qbf)[512 + t] = 0u;
        ((uint32_t*)qbf)[768 + (t & 255)] = 0u;
    }
    __syncthreads();

    bf16x8 qf[4];
    #pragma unroll
    for (int ks = 0; ks < 4; ++ks) qf[ks] = *(const bf16x8*)&qbf[lr][ks * 32 + lg * 8];

    f32x4 apv[8];
    #pragma unroll
    for (int dt = 0; dt < 8; ++dt) apv[dt] = (f32x4){0.f, 0.f, 0.f, 0.f};
    float cs0 = 0.f, cs1 = 0.f, cs2 = 0.f, cs3 = 0.f;

    const size_t kkb = (size_t)(b * kN) * 128;
    const size_t vvb = (size_t)b * 128 * (size_t)kN;

    #pragma unroll
    for (int ch = 0; ch < 2; ++ch) {
        const int nbase = nb * 256 + w * 64 + ch * 32;
        #pragma unroll
        for (int c2 = 0; c2 < 2; ++c2) {
            const int n16 = nbase + 16 * c2;
            f32x4 pl = (f32x4){0.f, 0.f, 0.f, 0.f};
            #pragma unroll
            for (int ks = 0; ks < 4; ++ks) {
                bf16x8 bfr = *(const bf16x8*)(kk + kkb + (size_t)(n16 + lr) * 128 + ks * 32 + lg * 8);
                pl = __builtin_amdgcn_mfma_f32_16x16x32_bf16(qf[ks], bfr, pl, 0, 0, 0);
            }
            float m = fmaxf(fmaxf(pl[0], pl[1]), fmaxf(pl[2], pl[3]));
            m = fmaxf(m, __shfl_xor(m, 16));
            float e0 = __expf(pl[0] - m), e1 = __expf(pl[1] - m);
            float e2 = __expf(pl[2] - m), e3 = __expf(pl[3] - m);
            float smv = e0 + e1 + e2 + e3;
            smv += __shfl_xor(smv, 16);
            const float inv = 1.0f / smv;
            const float a0 = e0 * inv, a1 = e1 * inv, a2 = e2 * inv, a3 = e3 * inv;
            if (lg < 2) {
                cs0 += a0; cs1 += a1; cs2 += a2; cs3 += a3;
                if (wvis)
                    *(float4*)(attn_out + ((size_t)(b * kN) + n16 + lr) * 8 + lg * 4) =
                        make_float4(a0, a1, a2, a3);
                const int s0 = lg * 4, nn = 16 * c2 + lr;
                aB[w][s0 + 0][nn] = bf1(a0);
                aB[w][s0 + 1][nn] = bf1(a1);
                aB[w][s0 + 2][nn] = bf1(a2);
                aB[w][s0 + 3][nn] = bf1(a3);
            }
        }
        bf16x8 af = *(const bf16x8*)&aB[w][lr][lg * 8];
        #pragma unroll
        for (int dt = 0; dt < 8; ++dt) {
            bf16x8 vfr = *(const bf16x8*)(vvT + vvb + (size_t)(16 * dt + lr) * kN + nbase + lg * 8);
            apv[dt] = __builtin_amdgcn_mfma_f32_16x16x32_bf16(vfr, af, apv[dt], 0, 0, 0);
        }
    }

    if (lr < 8) {
        #pragma unroll
        for (int dt = 0; dt < 8; ++dt)
            *(float4*)&pwU[w][lr][16 * dt + lg * 4] =
                make_float4(apv[dt][0], apv[dt][1], apv[dt][2], apv[dt][3]);
    }
    #pragma unroll
    for (int d = 8; d >= 1; d >>= 1) {
        cs0 += __shfl_xor(cs0, d); cs1 += __shfl_xor(cs1, d);
        cs2 += __shfl_xor(cs2, d); cs3 += __shfl_xor(cs3, d);
    }
    if (lr == 0 && lg < 2) {
        csL[w][lg * 4 + 0] = cs0; csL[w][lg * 4 + 1] = cs1;
        csL[w][lg * 4 + 2] = cs2; csL[w][lg * 4 + 3] = cs3;
    }
    __syncthreads();
    {
        const int s = t >> 5, dq = t & 31;
        float4 r0 = *(const float4*)&pwU[0][s][dq * 4];
        float4 r1 = *(const float4*)&pwU[1][s][dq * 4];
        float4 r2 = *(const float4*)&pwU[2][s][dq * 4];
        float4 r3 = *(const float4*)&pwU[3][s][dq * 4];
        float4 o;
        o.x = r0.x + r1.x + r2.x + r3.x;
        o.y = r0.y + r1.y + r2.y + r3.y;
        o.z = r0.z + r1.z + r2.z + r3.z;
        o.w = r0.w + r1.w + r2.w + r3.w;
        *(float4*)(pu + (size_t)blk * 1024 + s * 128 + dq * 4) = o;
    }
    if (t < 8) pcs[blk * 8 + t] = csL[0][t] + csL[1][t] + csL[2][t] + csL[3][t];
}

// ---------------- K3: updates, GRUs, MLPs, new logits; fused next-iter slots/q ----------------
__global__ __launch_bounds__(256) void kupdate(
    const float* __restrict__ pu, const float* __restrict__ pcs, const int nblk,
    const float* __restrict__ vvsum, float* __restrict__ sint,
    float* __restrict__ sext, float* __restrict__ lpi,
    const float* __restrict__ giWih, const float* __restrict__ giWhh,
    const float* __restrict__ gibih, const float* __restrict__ gibhh,
    const float* __restrict__ geWih, const float* __restrict__ geWhh,
    const float* __restrict__ gebih, const float* __restrict__ gebhh,
    const float* __restrict__ miW1, const float* __restrict__ mib1,
    const float* __restrict__ miW2, const float* __restrict__ mib2,
    const float* __restrict__ meW1, const float* __restrict__ meb1,
    const float* __restrict__ meW2, const float* __restrict__ meb2,
    const float* __restrict__ lmig, const float* __restrict__ lmib,
    const float* __restrict__ lmeg, const float* __restrict__ lmeb,
    const float* __restrict__ pT, float* __restrict__ out, const int last,
    const float* __restrict__ gumN, const void* __restrict__ taup,
    const float* __restrict__ p, const float* __restrict__ sbck,
    const float* __restrict__ Wq, float* __restrict__ q)
{
    __shared__ float uL[128], hA[64], hB[64];
    __shared__ float g1[192], g2[192];
    __shared__ float tmp[256];
    __shared__ float red[256];
    __shared__ float outE[64], outI[64];
    __shared__ float lgL[64];
    __shared__ float sv[128];
    const int bs = blockIdx.x;   // 512
    const int b = bs >> 3, s = bs & 7;
    const int t = threadIdx.x;   // 256

    if (t < 128) {
        float num = 0.f;
        for (int nb = 0; nb < nblk; ++nb) num += pu[((size_t)(b * nblk + nb)) * 1024 + s * 128 + t];
        float den = 4096.0f * kEPS;
        for (int nb = 0; nb < nblk; ++nb) den += pcs[(b * nblk + nb) * 8 + s];
        uL[t] = (num + kEPS * vvsum[b * 128 + t]) / den;
    } else if (t < 192) {
        hA[t - 128] = sext[bs * 64 + (t - 128)];
    } else {
        hB[t - 192] = sint[bs * 64 + (t - 192)];
    }
    __syncthreads();
    if (t < 192) {
        float a = gebih[t], bb = gebhh[t];
        for (int k = 0; k < 64; ++k) {
            a  = fmaf(uL[64 + k], geWih[k * 192 + t], a);
            bb = fmaf(hA[k],      geWhh[k * 192 + t], bb);
        }
        g1[t] = a; g2[t] = bb;
    }
    __syncthreads();
    if (t < 64) {
        float r = sigf(g1[t] + g2[t]);
        float z = sigf(g1[64 + t] + g2[64 + t]);
        float nn = tanhf(g1[128 + t] + r * g2[128 + t]);
        outE[t] = (1.0f - z) * nn + z * hA[t];
    }
    __syncthreads();
    if (t < 192) {
        float a = gibih[t], bb = gibhh[t];
        for (int k = 0; k < 64; ++k) {
            a  = fmaf(uL[k], giWih[k * 192 + t], a);
            bb = fmaf(hB[k], giWhh[k * 192 + t], bb);
        }
        g1[t] = a; g2[t] = bb;
    }
    __syncthreads();
    if (t < 64) {
        float r = sigf(g1[t] + g2[t]);
        float z = sigf(g1[64 + t] + g2[64 + t]);
        float nn = tanhf(g1[128 + t] + r * g2[128 + t]);
        outI[t] = (1.0f - z) * nn + z * hB[t];
    }
    __syncthreads();
    if (!last) {
        // MLP ext
        if (t < 64) {
            float v = outE[t];
            float sm = v, sq = v * v;
            #pragma unroll
            for (int d = 32; d >= 1; d >>= 1) { sm += __shfl_xor(sm, d); sq += __shfl_xor(sq, d); }
            float m = sm * (1.0f / 64.0f), var = sq * (1.0f / 64.0f) - m * m;
            g1[t] = (v - m) * rsqrtf(var + kLNE) * lmeg[t] + lmeb[t];
        }
        __syncthreads();
        {
            float a = meb1[t];
            for (int k = 0; k < 64; ++k) a = fmaf(g1[k], meW1[k * 256 + t], a);
            tmp[t] = fmaxf(a, 0.0f);
        }
        __syncthreads();
        {
            const int c = t & 63, qq = t >> 6;
            float o = 0.f;
            for (int jj = 0; jj < 64; ++jj) {
                const int j = qq * 64 + jj;
                o = fmaf(tmp[j], meW2[j * 64 + c], o);
            }
            red[t] = o;
        }
        __syncthreads();
        if (t < 64) outE[t] += meb2[t] + red[t] + red[64 + t] + red[128 + t] + red[192 + t];
        __syncthreads();
        // MLP int
        if (t < 64) {
            float v = outI[t];
            float sm = v, sq = v * v;
            #pragma unroll
            for (int d = 32; d >= 1; d >>= 1) { sm += __shfl_xor(sm, d); sq += __shfl_xor(sq, d); }
            float m = sm * (1.0f / 64.0f), var = sq * (1.0f / 64.0f) - m * m;
            g1[t] = (v - m) * rsqrtf(var + kLNE) * lmig[t] + lmib[t];
        }
        __syncthreads();
        {
            float a = mib1[t];
            for (int k = 0; k < 64; ++k) a = fmaf(g1[k], miW1[k * 256 + t], a);
            tmp[t] = fmaxf(a, 0.0f);
        }
        __syncthreads();
        {
            const int c = t & 63, qq = t >> 6;
            float o = 0.f;
            for (int jj = 0; jj < 64; ++jj) {
                const int j = qq * 64 + jj;
                o = fmaf(tmp[j], miW2[j * 64 + c], o);
            }
            red[t] = o;
        }
        __syncthreads();
        if (t < 64) outI[t] += mib2[t] + red[t] + red[64 + t] + red[128 + t] + red[192 + t];
        __syncthreads();
    }
    if (t < 64) {
        float lg = 0.f;
        for (int k = 0; k < 64; ++k) lg = fmaf(outI[k], pT[k * 64 + t], lg);
        lg *= kISC;
        lgL[t] = lg;
        if (last) { if (s > 0) out[28672 + (b * 7 + (s - 1)) * 64 + t] = lg; }
    } else if (t < 128) {
        int c = t - 64;
        float v = outE[c];
        sext[bs * 64 + c] = v;
        if (last && s > 0) out[(b * 7 + (s - 1)) * 64 + c] = v;
    }
    if (last) return;

    __syncthreads();
    const float inv_tau = read_tau(taup);
    if (t < 64) {
        float l = (lgL[t] + gumN[bs * 64 + t]) * inv_tau;
        float m = l;
        #pragma unroll
        for (int d = 32; d >= 1; d >>= 1) m = fmaxf(m, __shfl_xor(m, d));
        float e = __expf(l - m);
        float smv = e;
        #pragma unroll
        for (int d = 32; d >= 1; d >>= 1) smv += __shfl_xor(smv, d);
        tmp[t] = e / smv;   // pi
    }
    __syncthreads();
    if (t < 64) {
        float acc = 0.f;
        for (int c = 0; c < 64; ++c) acc += tmp[c] * p[c * 64 + t];
        sint[bs * 64 + t] = acc;
        if (s == 0) {
            sv[t]      = sbck[b * 128 + t];
            sv[64 + t] = sbck[b * 128 + 64 + t];
        } else {
            sv[t]      = acc;
            sv[64 + t] = outE[t];
        }
    }
    __syncthreads();
    if (t < 128) {
        float acc = 0.f;
        for (int k = 0; k < 128; ++k) acc += sv[k] * Wq[k * 128 + t];
        q[bs * 128 + t] = acc;
    }
}

extern "C" void kernel_launch(void* const* d_in, const int* in_sizes, int n_in,
                              void* d_out, int out_size, void* d_ws, size_t ws_size,
                              hipStream_t stream)
{
    (void)in_sizes; (void)n_in; (void)out_size; (void)ws_size;
    const float* slots_bck = (const float*)d_in[0];
    const float* inputs    = (const float*)d_in[1];
    const float* protos    = (const float*)d_in[2];
    const float* ext_noise = (const float*)d_in[3];
    const float* int_noise = (const float*)d_in[4];
    const float* gumbel    = (const float*)d_in[5];
    const void*  taup      = d_in[6];
    const float* ext_mu    = (const float*)d_in[7];
    const float* ext_ls    = (const float*)d_in[8];
    const float* int_mu    = (const float*)d_in[9];
    const float* int_ls    = (const float*)d_in[10];
    const float* ln_in_g   = (const float*)d_in[11];
    const float* ln_in_b   = (const float*)d_in[12];
    const float* ln_p_g    = (const float*)d_in[13];
    const float* ln_p_b    = (const float*)d_in[14];
    const float* ln_mi_g   = (const float*)d_in[15];
    const float* ln_mi_b   = (const float*)d_in[16];
    const float* ln_me_g   = (const float*)d_in[17];
    const float* ln_me_b   = (const float*)d_in[18];
    const float* Wq        = (const float*)d_in[19];
    const float* Wk        = (const float*)d_in[20];
    const float* Wv        = (const float*)d_in[21];
    const float* Wp        = (const float*)d_in[22];
    const float* giWih     = (const float*)d_in[23];
    const float* giWhh     = (const float*)d_in[24];
    const float* gibih     = (const float*)d_in[25];
    const float* gibhh     = (const float*)d_in[26];
    const float* geWih     = (const float*)d_in[27];
    const float* geWhh     = (const float*)d_in[28];
    const float* gebih     = (const float*)d_in[29];
    const float* gebhh     = (const float*)d_in[30];
    const float* miW1      = (const float*)d_in[31];
    const float* mib1      = (const float*)d_in[32];
    const float* miW2      = (const float*)d_in[33];
    const float* mib2      = (const float*)d_in[34];
    const float* meW1      = (const float*)d_in[35];
    const float* meb1      = (const float*)d_in[36];
    const float* meW2      = (const float*)d_in[37];
    const float* meb2      = (const float*)d_in[38];
    float* out = (float*)d_out;

    char* ws = (char*)d_ws;
    size_t o = 0;
    auto alloc = [&](size_t bytes) { size_t r = o; o += (bytes + 255) & ~(size_t)255; return r; };
    u16*   kkp   = (u16*)  (ws + alloc((size_t)kB * kN * 128 * 2));
    u16*   vvTp  = (u16*)  (ws + alloc((size_t)kB * kN * 128 * 2));
    u16*   WT    = (u16*)  (ws + alloc(256 * 128 * 2));
    float* vpart = (float*)(ws + alloc((size_t)4096 * 128 * 4));
    float* vvsum = (float*)(ws + alloc(8192 * 4));
    float* pbuf  = (float*)(ws + alloc(4096 * 4));
    float* pT    = (float*)(ws + alloc(4096 * 4));
    float* sext  = (float*)(ws + alloc(32768 * 4));
    float* lpi   = (float*)(ws + alloc(32768 * 4));
    float* sint  = (float*)(ws + alloc(32768 * 4));
    float* q     = (float*)(ws + alloc(65536 * 4));
    float* pu    = (float*)(ws + alloc((size_t)4096 * 1024 * 4));
    float* pcs   = (float*)(ws + alloc(4096 * 8 * 4));

    ksetup<<<257, 256, 0, stream>>>(ext_mu, ext_ls, int_mu, int_ls, ext_noise, int_noise,
                                    sext, lpi, Wk, Wv, WT, protos, Wp, ln_p_g, ln_p_b, pbuf, pT);
    kslots<<<512, 128, 0, stream>>>(lpi, gumbel, taup, pbuf, slots_bck, sext, Wq, sint, q);
    kmain<<<4096, 256, 0, stream>>>(inputs, WT, ln_in_g, ln_in_b, q, kkp, vvTp, vpart, pu, pcs);
    kvvsum<<<32, 256, 0, stream>>>(vpart, vvsum);

    for (int i = 0; i < 3; ++i) {
        const int last = (i == 2);
        if (i > 0)
            kattn<<<1024, 256, 0, stream>>>(kkp, vvTp, q, out + 57344, pu, pcs, last ? 1 : 0);
        kupdate<<<512, 256, 0, stream>>>(pu, pcs, (i == 0) ? 64 : 16, vvsum, sint, sext, lpi,
                                         giWih, giWhh, gibih, gibhh,
                                         geWih, geWhh, gebih, gebhh,
                                         miW1, mib1, miW2, mib2,
                                         meW1, meb1, meW2, meb2,
                                         ln_mi_g, ln_mi_b, ln_me_g, ln_me_b,
                                         pT, out, last,
                                         gumbel + (size_t)(i + 1 < 3 ? i + 1 : 0) * 32768,
                                         taup, pbuf, slots_bck, Wq, q);
    }
}